// Round 1
// baseline (2115.571 us; speedup 1.0000x reference)
//
#include <hip/hip_runtime.h>
#include <math.h>

#define NN 50000
#define NE 600000
// D = H = 128 hard-coded

__device__ __forceinline__ float silu_f(float x) {
    return x / (1.0f + __expf(-x));
}

// ---------------- Kernel 1: node LayerNorm  hn = LN(h) -------------------
__global__ __launch_bounds__(256) void ln_nodes_kernel(
    const float* __restrict__ h, const float* __restrict__ g,
    const float* __restrict__ b, float* __restrict__ hn) {
    int node = blockIdx.x * 4 + (threadIdx.x >> 6);
    int lane = threadIdx.x & 63;
    if (node >= NN) return;
    const float* row = h + (size_t)node * 128;
    float x0 = row[lane], x1 = row[lane + 64];
    float s = x0 + x1, s2 = x0 * x0 + x1 * x1;
#pragma unroll
    for (int off = 32; off; off >>= 1) {
        s  += __shfl_xor(s, off);
        s2 += __shfl_xor(s2, off);
    }
    float m = s * (1.0f / 128.0f);
    float v = s2 * (1.0f / 128.0f) - m * m;
    float inv = rsqrtf(v + 1e-5f);
    float* orow = hn + (size_t)node * 128;
    orow[lane]      = (x0 - m) * inv * g[lane]      + b[lane];
    orow[lane + 64] = (x1 - m) * inv * g[lane + 64] + b[lane + 64];
}

// ---------------- Kernel 2: fused edge kernel ----------------------------
// 32 edges per 256-thread block. thread: f = t&127 (feature), grp = t>>7
// (edge half: grp*16 .. grp*16+15).
__global__ __launch_bounds__(256) void edge_kernel(
    const float* __restrict__ hn, const int* __restrict__ erow,
    const int* __restrict__ ecol, const float* __restrict__ coord,
    const float* __restrict__ eg, const float* __restrict__ ebias,
    const float* __restrict__ w1, const float* __restrict__ b1,
    const float* __restrict__ w2, const float* __restrict__ b2,
    const float* __restrict__ cw1, const float* __restrict__ cb1,
    const float* __restrict__ cw2,
    float* __restrict__ agg, float* __restrict__ svec,
    float* __restrict__ cnt) {
    __shared__ float hnr[32][128];   // hn[row]   (later reused as p-buffer)
    __shared__ float hnc[32][128];   // hn[col]   (later reused as buf2)
    __shared__ float ebuf[32][128];  // e1 -> e (post-LN)
    __shared__ float cdS[32][3];
    __shared__ float radS[32];
    __shared__ int   rids[32], cids[32];

    int e0 = blockIdx.x * 32;
    int t = threadIdx.x;
    int ne = NE - e0; if (ne > 32) ne = 32;

    if (t < 32) {
        int e = e0 + t;
        rids[t] = (t < ne) ? erow[e] : 0;
    } else if (t < 64) {
        int tt = t - 32;
        int e = e0 + tt;
        cids[tt] = (tt < ne) ? ecol[e] : 0;
    }
    __syncthreads();
    // gather hn rows (coalesced per row)
    for (int idx = t; idx < 32 * 128; idx += 256) {
        int e = idx >> 7, f = idx & 127;
        hnr[e][f] = hn[(size_t)rids[e] * 128 + f];
        hnc[e][f] = hn[(size_t)cids[e] * 128 + f];
    }
    if (t < 32) {
        int r = rids[t], c = cids[t];
        float dx = coord[r * 3 + 0] - coord[c * 3 + 0];
        float dy = coord[r * 3 + 1] - coord[c * 3 + 1];
        float dz = coord[r * 3 + 2] - coord[c * 3 + 2];
        cdS[t][0] = dx; cdS[t][1] = dy; cdS[t][2] = dz;
        radS[t] = dx * dx + dy * dy + dz * dz;
    }
    __syncthreads();

    int f = t & 127;
    int eb0 = (t >> 7) * 16;

    // ---- layer 1: e1 = silu([hnr hnc radial] @ w1 + b1) ----
    float acc[16];
#pragma unroll
    for (int e = 0; e < 16; e++) acc[e] = 0.0f;
    for (int k4 = 0; k4 < 32; k4++) {
        float wv0 = w1[(size_t)(4 * k4 + 0) * 128 + f];
        float wv1 = w1[(size_t)(4 * k4 + 1) * 128 + f];
        float wv2 = w1[(size_t)(4 * k4 + 2) * 128 + f];
        float wv3 = w1[(size_t)(4 * k4 + 3) * 128 + f];
#pragma unroll
        for (int e = 0; e < 16; e++) {
            float4 xv = *(const float4*)&hnr[eb0 + e][4 * k4];
            acc[e] += xv.x * wv0 + xv.y * wv1 + xv.z * wv2 + xv.w * wv3;
        }
    }
    for (int k4 = 0; k4 < 32; k4++) {
        float wv0 = w1[(size_t)(128 + 4 * k4 + 0) * 128 + f];
        float wv1 = w1[(size_t)(128 + 4 * k4 + 1) * 128 + f];
        float wv2 = w1[(size_t)(128 + 4 * k4 + 2) * 128 + f];
        float wv3 = w1[(size_t)(128 + 4 * k4 + 3) * 128 + f];
#pragma unroll
        for (int e = 0; e < 16; e++) {
            float4 xv = *(const float4*)&hnc[eb0 + e][4 * k4];
            acc[e] += xv.x * wv0 + xv.y * wv1 + xv.z * wv2 + xv.w * wv3;
        }
    }
    {
        float wr = w1[(size_t)256 * 128 + f];
        float b1f = b1[f];
#pragma unroll
        for (int e = 0; e < 16; e++) {
            acc[e] += radS[eb0 + e] * wr;
            acc[e] = silu_f(acc[e] + b1f);
        }
    }
#pragma unroll
    for (int e = 0; e < 16; e++) ebuf[eb0 + e][f] = acc[e];
    __syncthreads();

    // ---- layer 2: e2 = silu(e1 @ w2 + b2) -> hnc buffer (buf2) ----
    float acc2[16];
#pragma unroll
    for (int e = 0; e < 16; e++) acc2[e] = 0.0f;
    for (int k4 = 0; k4 < 32; k4++) {
        float wv0 = w2[(size_t)(4 * k4 + 0) * 128 + f];
        float wv1 = w2[(size_t)(4 * k4 + 1) * 128 + f];
        float wv2 = w2[(size_t)(4 * k4 + 2) * 128 + f];
        float wv3 = w2[(size_t)(4 * k4 + 3) * 128 + f];
#pragma unroll
        for (int e = 0; e < 16; e++) {
            float4 xv = *(const float4*)&ebuf[eb0 + e][4 * k4];
            acc2[e] += xv.x * wv0 + xv.y * wv1 + xv.z * wv2 + xv.w * wv3;
        }
    }
    {
        float b2f = b2[f];
#pragma unroll
        for (int e = 0; e < 16; e++) acc2[e] = silu_f(acc2[e] + b2f);
    }
    __syncthreads();  // ebuf reads done
#pragma unroll
    for (int e = 0; e < 16; e++) hnc[eb0 + e][f] = acc2[e];  // buf2
    __syncthreads();

    // ---- edge LayerNorm (wave w handles edges 8w..8w+7) + agg scatter ----
    {
        int wv = t >> 6, lane = t & 63;
#pragma unroll
        for (int i = 0; i < 8; i++) {
            int e = wv * 8 + i;
            float x0 = hnc[e][lane], x1 = hnc[e][lane + 64];
            float s = x0 + x1, s2 = x0 * x0 + x1 * x1;
#pragma unroll
            for (int off = 32; off; off >>= 1) {
                s  += __shfl_xor(s, off);
                s2 += __shfl_xor(s2, off);
            }
            float m = s * (1.0f / 128.0f);
            float va = s2 * (1.0f / 128.0f) - m * m;
            float inv = rsqrtf(va + 1e-5f);
            float y0 = (x0 - m) * inv * eg[lane]      + ebias[lane];
            float y1 = (x1 - m) * inv * eg[lane + 64] + ebias[lane + 64];
            ebuf[e][lane] = y0; ebuf[e][lane + 64] = y1;
            if (e < ne) {
                size_t r = (size_t)rids[e] * 128;
                atomicAdd(&agg[r + lane], y0);
                atomicAdd(&agg[r + lane + 64], y1);
            }
        }
    }
    __syncthreads();

    // ---- coord MLP: p_f = silu(e @ cw1 + cb1)_f * cw2_f ; scale = sum_f p
    float acc3[16];
#pragma unroll
    for (int e = 0; e < 16; e++) acc3[e] = 0.0f;
    for (int k4 = 0; k4 < 32; k4++) {
        float wv0 = cw1[(size_t)(4 * k4 + 0) * 128 + f];
        float wv1 = cw1[(size_t)(4 * k4 + 1) * 128 + f];
        float wv2 = cw1[(size_t)(4 * k4 + 2) * 128 + f];
        float wv3 = cw1[(size_t)(4 * k4 + 3) * 128 + f];
#pragma unroll
        for (int e = 0; e < 16; e++) {
            float4 xv = *(const float4*)&ebuf[eb0 + e][4 * k4];
            acc3[e] += xv.x * wv0 + xv.y * wv1 + xv.z * wv2 + xv.w * wv3;
        }
    }
    {
        float cb1f = cb1[f], cw2f = cw2[f];
#pragma unroll
        for (int e = 0; e < 16; e++)
            hnr[eb0 + e][f] = silu_f(acc3[e] + cb1f) * cw2f;  // p-buffer
    }
    __syncthreads();

    // reduce p over features -> scale; scatter trans + cnt
    {
        int wv = t >> 6, lane = t & 63;
#pragma unroll
        for (int i = 0; i < 8; i++) {
            int e = wv * 8 + i;
            float p = hnr[e][lane] + hnr[e][lane + 64];
#pragma unroll
            for (int off = 32; off; off >>= 1) p += __shfl_xor(p, off);
            if (e < ne && lane < 4) {
                int r = rids[e];
                if (lane < 3) atomicAdd(&svec[r * 3 + lane], cdS[e][lane] * p);
                else          atomicAdd(&cnt[r], 1.0f);
            }
        }
    }
}

// ---------------- Kernel 3: node MLP + residual + coord_out --------------
__global__ __launch_bounds__(256) void node_kernel(
    const float* __restrict__ h, const float* __restrict__ hn,
    const float* __restrict__ agg, const float* __restrict__ coord,
    const float* __restrict__ nw1, const float* __restrict__ nb1,
    const float* __restrict__ nw2, const float* __restrict__ nb2,
    const float* __restrict__ svec, const float* __restrict__ cnt,
    float* __restrict__ hout, float* __restrict__ cout) {
    __shared__ float hno[32][128];
    __shared__ float ago[32][128];
    __shared__ float nb[32][128];

    int n0 = blockIdx.x * 32;
    int t = threadIdx.x;
    int nn = NN - n0; if (nn > 32) nn = 32;

    for (int idx = t; idx < 32 * 128; idx += 256) {
        int e = idx >> 7, f = idx & 127;
        int n = n0 + e;
        if (e < nn) {
            hno[e][f] = hn[(size_t)n * 128 + f];
            ago[e][f] = agg[(size_t)n * 128 + f];
        } else {
            hno[e][f] = 0.0f; ago[e][f] = 0.0f;
        }
    }
    __syncthreads();

    int f = t & 127;
    int eb0 = (t >> 7) * 16;

    float acc[16];
#pragma unroll
    for (int e = 0; e < 16; e++) acc[e] = 0.0f;
    for (int k4 = 0; k4 < 32; k4++) {
        float wv0 = nw1[(size_t)(4 * k4 + 0) * 128 + f];
        float wv1 = nw1[(size_t)(4 * k4 + 1) * 128 + f];
        float wv2 = nw1[(size_t)(4 * k4 + 2) * 128 + f];
        float wv3 = nw1[(size_t)(4 * k4 + 3) * 128 + f];
#pragma unroll
        for (int e = 0; e < 16; e++) {
            float4 xv = *(const float4*)&hno[eb0 + e][4 * k4];
            acc[e] += xv.x * wv0 + xv.y * wv1 + xv.z * wv2 + xv.w * wv3;
        }
    }
    for (int k4 = 0; k4 < 32; k4++) {
        float wv0 = nw1[(size_t)(128 + 4 * k4 + 0) * 128 + f];
        float wv1 = nw1[(size_t)(128 + 4 * k4 + 1) * 128 + f];
        float wv2 = nw1[(size_t)(128 + 4 * k4 + 2) * 128 + f];
        float wv3 = nw1[(size_t)(128 + 4 * k4 + 3) * 128 + f];
#pragma unroll
        for (int e = 0; e < 16; e++) {
            float4 xv = *(const float4*)&ago[eb0 + e][4 * k4];
            acc[e] += xv.x * wv0 + xv.y * wv1 + xv.z * wv2 + xv.w * wv3;
        }
    }
    {
        float b1f = nb1[f];
#pragma unroll
        for (int e = 0; e < 16; e++) nb[eb0 + e][f] = silu_f(acc[e] + b1f);
    }
    __syncthreads();

    float acc2[16];
#pragma unroll
    for (int e = 0; e < 16; e++) acc2[e] = 0.0f;
    for (int k4 = 0; k4 < 32; k4++) {
        float wv0 = nw2[(size_t)(4 * k4 + 0) * 128 + f];
        float wv1 = nw2[(size_t)(4 * k4 + 1) * 128 + f];
        float wv2 = nw2[(size_t)(4 * k4 + 2) * 128 + f];
        float wv3 = nw2[(size_t)(4 * k4 + 3) * 128 + f];
#pragma unroll
        for (int e = 0; e < 16; e++) {
            float4 xv = *(const float4*)&nb[eb0 + e][4 * k4];
            acc2[e] += xv.x * wv0 + xv.y * wv1 + xv.z * wv2 + xv.w * wv3;
        }
    }
    {
        float b2f = nb2[f];
#pragma unroll
        for (int e = 0; e < 16; e++) {
            int n = n0 + eb0 + e;
            if (eb0 + e < nn)
                hout[(size_t)n * 128 + f] =
                    acc2[e] + b2f + h[(size_t)n * 128 + f];
        }
    }
    // coord_out
    if (t < 96) {
        int i = t / 3, j = t % 3;
        int n = n0 + i;
        if (i < nn) {
            float c = cnt[n]; c = fmaxf(c, 1.0f);
            cout[n * 3 + j] = coord[n * 3 + j] + svec[n * 3 + j] / c;
        }
    }
}

extern "C" void kernel_launch(void* const* d_in, const int* in_sizes, int n_in,
                              void* d_out, int out_size, void* d_ws, size_t ws_size,
                              hipStream_t stream) {
    const float* h        = (const float*)d_in[0];
    const int*   eidx     = (const int*)d_in[1];
    const float* coord    = (const float*)d_in[2];
    const float* nlg      = (const float*)d_in[3];
    const float* nlb      = (const float*)d_in[4];
    const float* elg      = (const float*)d_in[5];
    const float* elb      = (const float*)d_in[6];
    const float* ew1      = (const float*)d_in[7];
    const float* eb1      = (const float*)d_in[8];
    const float* ew2      = (const float*)d_in[9];
    const float* eb2      = (const float*)d_in[10];
    const float* nw1      = (const float*)d_in[11];
    const float* nb1      = (const float*)d_in[12];
    const float* nw2      = (const float*)d_in[13];
    const float* nb2      = (const float*)d_in[14];
    const float* cw1      = (const float*)d_in[15];
    const float* cb1      = (const float*)d_in[16];
    const float* cw2      = (const float*)d_in[17];

    float* hout = (float*)d_out;                 // [N,128]
    float* cout = (float*)d_out + (size_t)NN * 128;  // [N,3]

    // workspace layout (floats): hn | agg | svec | cnt
    float* hn   = (float*)d_ws;
    float* agg  = hn  + (size_t)NN * 128;
    float* svec = agg + (size_t)NN * 128;
    float* cnt  = svec + (size_t)NN * 3;
    // zero agg + svec + cnt (contiguous)
    size_t zbytes = ((size_t)NN * 128 + (size_t)NN * 3 + NN) * sizeof(float);
    hipMemsetAsync(agg, 0, zbytes, stream);

    const int* erow = eidx;
    const int* ecol = eidx + NE;

    ln_nodes_kernel<<<(NN + 3) / 4, 256, 0, stream>>>(h, nlg, nlb, hn);
    edge_kernel<<<(NE + 31) / 32, 256, 0, stream>>>(
        hn, erow, ecol, coord, elg, elb, ew1, eb1, ew2, eb2, cw1, cb1, cw2,
        agg, svec, cnt);
    node_kernel<<<(NN + 31) / 32, 256, 0, stream>>>(
        h, hn, agg, coord, nw1, nb1, nw2, nb2, svec, cnt, hout, cout);
}

// Round 2
// 707.338 us; speedup vs baseline: 2.9909x; 2.9909x over previous
//
#include <hip/hip_runtime.h>
#include <math.h>

#define NN 50000
#define NE 600000
// D = H = 128 hard-coded. NE % 32 == 0 (18750 edge tiles, no tail).

typedef __attribute__((ext_vector_type(8))) short bf16x8;
typedef __attribute__((ext_vector_type(4))) float f32x4;

__device__ __forceinline__ float silu_f(float x) {
    return x / (1.0f + __expf(-x));
}
__device__ __forceinline__ unsigned short f2bf(float x) {
    unsigned int u = __float_as_uint(x);
    return (unsigned short)((u + 0x7FFFu + ((u >> 16) & 1u)) >> 16);
}
__device__ __forceinline__ float bf2f(unsigned short s) {
    return __uint_as_float(((unsigned int)s) << 16);
}

// ---------------- Kernel 0: weight transpose+cast to bf16 ----------------
// w1T[128][256], w2T[128][128], cw1T[128][128], nw1T[128][256], nw2T[128][128]
__global__ __launch_bounds__(256) void prep_weights(
    const float* __restrict__ w1, const float* __restrict__ w2,
    const float* __restrict__ cw1, const float* __restrict__ nw1,
    const float* __restrict__ nw2,
    unsigned short* __restrict__ w1T, unsigned short* __restrict__ w2T,
    unsigned short* __restrict__ cw1T, unsigned short* __restrict__ nw1T,
    unsigned short* __restrict__ nw2T) {
    int i = blockIdx.x * 256 + threadIdx.x;
    if (i < 32768) { int n = i >> 8, k = i & 255; w1T[i] = f2bf(w1[k * 128 + n]); return; }
    int j = i - 32768;
    if (j < 16384) { int n = j >> 7, k = j & 127; w2T[j] = f2bf(w2[k * 128 + n]); return; }
    j -= 16384;
    if (j < 16384) { int n = j >> 7, k = j & 127; cw1T[j] = f2bf(cw1[k * 128 + n]); return; }
    j -= 16384;
    if (j < 32768) { int n = j >> 8, k = j & 255; nw1T[j] = f2bf(nw1[k * 128 + n]); return; }
    j -= 32768;
    if (j < 16384) { int n = j >> 7, k = j & 127; nw2T[j] = f2bf(nw2[k * 128 + n]); return; }
}

// ---------------- Kernel 1: node LayerNorm -> hn (bf16) ------------------
__global__ __launch_bounds__(256) void ln_nodes_kernel(
    const float* __restrict__ h, const float* __restrict__ g,
    const float* __restrict__ b, unsigned short* __restrict__ hnb) {
    int node = blockIdx.x * 4 + (threadIdx.x >> 6);
    int lane = threadIdx.x & 63;
    if (node >= NN) return;
    const float* row = h + (size_t)node * 128;
    float x0 = row[lane], x1 = row[lane + 64];
    float s = x0 + x1, s2 = x0 * x0 + x1 * x1;
#pragma unroll
    for (int off = 32; off; off >>= 1) {
        s  += __shfl_xor(s, off);
        s2 += __shfl_xor(s2, off);
    }
    float m = s * (1.0f / 128.0f);
    float v = s2 * (1.0f / 128.0f) - m * m;
    float inv = rsqrtf(v + 1e-5f);
    unsigned short* orow = hnb + (size_t)node * 128;
    orow[lane]      = f2bf((x0 - m) * inv * g[lane]      + b[lane]);
    orow[lane + 64] = f2bf((x1 - m) * inv * g[lane + 64] + b[lane + 64]);
}

// swizzled ushort index into a [rows][128] bf16 LDS tile (16B chunk XOR)
__device__ __forceinline__ int swz128(int row, int col) {
    return row * 128 + (((col >> 3) ^ (row & 7)) << 3) + (col & 7);
}

// ---------------- Kernel 2: fused MFMA edge kernel -----------------------
// 256 threads = 4 waves; wave w owns output features [w*32, w*32+32).
// Grid-stride over 32-edge tiles. Weight B-fragments live in VGPRs.
__global__ __launch_bounds__(256, 2) void edge_kernel(
    const unsigned short* __restrict__ hnb,
    const int* __restrict__ erow, const int* __restrict__ ecol,
    const float* __restrict__ coord,
    const float* __restrict__ eg, const float* __restrict__ ebias,
    const float* __restrict__ w1, const float* __restrict__ b1,
    const float* __restrict__ b2, const float* __restrict__ cb1,
    const float* __restrict__ cw2,
    const unsigned short* __restrict__ w1T,
    const unsigned short* __restrict__ w2T,
    const unsigned short* __restrict__ cw1T,
    float* __restrict__ agg, float* __restrict__ svec,
    float* __restrict__ cnt) {
    __shared__ uint4 a1s[32 * 32];   // 16 KB: A1 tile [32 edges][256 k] bf16, swizzled
    __shared__ uint4 e1s[32 * 16];   //  8 KB: e1 then post-LN e [32][128] bf16
    __shared__ uint4 e2s[32 * 16];   //  8 KB: e2 (pre-LN)
    __shared__ float cdS[32][3];
    __shared__ float radS[32];
    __shared__ float scalef[32];
    __shared__ int   rids[32];

    const int t    = threadIdx.x;
    const int lane = t & 63;
    const int wave = t >> 6;
    const int l15  = lane & 15;
    const int g4   = lane >> 4;
    const int n0   = wave * 32;
    const int sw   = l15 & 7;

    // ---- preload weight fragments (B^T rows, contiguous K per lane) ----
    bf16x8 B1[2][8], B2[2][4], B3[2][4];
    float b1v[2], b2v[2], cb1v[2], cw2v[2], w1rv[2];
#pragma unroll
    for (int nf = 0; nf < 2; nf++) {
        int wr = n0 + nf * 16 + l15;          // output feature / B^T row
        const unsigned short* p1 = w1T + wr * 256 + g4 * 8;
#pragma unroll
        for (int kc = 0; kc < 8; kc++) B1[nf][kc] = *(const bf16x8*)(p1 + kc * 32);
        const unsigned short* p2 = w2T + wr * 128 + g4 * 8;
#pragma unroll
        for (int kc = 0; kc < 4; kc++) B2[nf][kc] = *(const bf16x8*)(p2 + kc * 32);
        const unsigned short* p3 = cw1T + wr * 128 + g4 * 8;
#pragma unroll
        for (int kc = 0; kc < 4; kc++) B3[nf][kc] = *(const bf16x8*)(p3 + kc * 32);
        b1v[nf]  = b1[wr];  b2v[nf] = b2[wr];
        cb1v[nf] = cb1[wr]; cw2v[nf] = cw2[wr];
        w1rv[nf] = w1[256 * 128 + wr];        // radial row of w1 (fp32)
    }
    const float egl0 = eg[lane],   egl1 = eg[lane + 64];
    const float ebl0 = ebias[lane], ebl1 = ebias[lane + 64];

    unsigned short* e1u = (unsigned short*)e1s;
    unsigned short* e2u = (unsigned short*)e2s;

    for (int tile = blockIdx.x; tile < NE / 32; tile += gridDim.x) {
        const int e0 = tile * 32;
        __syncthreads();   // previous tile fully consumed
        if (t < 32) {
            int r = erow[e0 + t], c = ecol[e0 + t];
            rids[t] = r;
            float dx = coord[r * 3 + 0] - coord[c * 3 + 0];
            float dy = coord[r * 3 + 1] - coord[c * 3 + 1];
            float dz = coord[r * 3 + 2] - coord[c * 3 + 2];
            cdS[t][0] = dx; cdS[t][1] = dy; cdS[t][2] = dz;
            radS[t] = dx * dx + dy * dy + dz * dz;
            scalef[t] = 0.0f;
        }
        // stage A1 = [hn[row] | hn[col]] as bf16, 16B chunks, swizzled
#pragma unroll
        for (int ii = 0; ii < 4; ii++) {
            int idx = t + ii * 256;
            int rr = idx >> 5, c = idx & 31;
            int nd = (c < 16) ? erow[e0 + rr] : ecol[e0 + rr];
            int cc = c & 15;
            uint4 d = *(const uint4*)(hnb + (size_t)nd * 128 + cc * 8);
            a1s[rr * 32 + (c ^ (rr & 7))] = d;
        }
        __syncthreads();

        // ---- GEMM1: e1 = silu(A1 @ w1[:256] + radial*w1r + b1) ----
        f32x4 a00 = {0,0,0,0}, a01 = {0,0,0,0}, a10 = {0,0,0,0}, a11 = {0,0,0,0};
        {
            const bf16x8* A = (const bf16x8*)a1s;
#pragma unroll
            for (int kc = 0; kc < 8; kc++) {
                int ch = kc * 4 + g4;
                bf16x8 f0 = A[l15 * 32 + (ch ^ sw)];
                bf16x8 f1 = A[(l15 + 16) * 32 + (ch ^ sw)];
                a00 = __builtin_amdgcn_mfma_f32_16x16x32_bf16(f0, B1[0][kc], a00, 0, 0, 0);
                a01 = __builtin_amdgcn_mfma_f32_16x16x32_bf16(f0, B1[1][kc], a01, 0, 0, 0);
                a10 = __builtin_amdgcn_mfma_f32_16x16x32_bf16(f1, B1[0][kc], a10, 0, 0, 0);
                a11 = __builtin_amdgcn_mfma_f32_16x16x32_bf16(f1, B1[1][kc], a11, 0, 0, 0);
            }
        }
#pragma unroll
        for (int mf = 0; mf < 2; mf++) {
#pragma unroll
            for (int r = 0; r < 4; r++) {
                int row = mf * 16 + g4 * 4 + r;
                float rad = radS[row];
#pragma unroll
                for (int nf = 0; nf < 2; nf++) {
                    float v = mf ? (nf ? a11[r] : a10[r]) : (nf ? a01[r] : a00[r]);
                    v = silu_f(v + rad * w1rv[nf] + b1v[nf]);
                    int col = n0 + nf * 16 + l15;
                    e1u[swz128(row, col)] = f2bf(v);
                }
            }
        }
        __syncthreads();

        // ---- GEMM2: e2 = silu(e1 @ w2 + b2) ----
        f32x4 c00 = {0,0,0,0}, c01 = {0,0,0,0}, c10 = {0,0,0,0}, c11 = {0,0,0,0};
        {
            const bf16x8* A = (const bf16x8*)e1s;
#pragma unroll
            for (int kc = 0; kc < 4; kc++) {
                int ch = kc * 4 + g4;
                bf16x8 f0 = A[l15 * 16 + (ch ^ sw)];
                bf16x8 f1 = A[(l15 + 16) * 16 + (ch ^ sw)];
                c00 = __builtin_amdgcn_mfma_f32_16x16x32_bf16(f0, B2[0][kc], c00, 0, 0, 0);
                c01 = __builtin_amdgcn_mfma_f32_16x16x32_bf16(f0, B2[1][kc], c01, 0, 0, 0);
                c10 = __builtin_amdgcn_mfma_f32_16x16x32_bf16(f1, B2[0][kc], c10, 0, 0, 0);
                c11 = __builtin_amdgcn_mfma_f32_16x16x32_bf16(f1, B2[1][kc], c11, 0, 0, 0);
            }
        }
#pragma unroll
        for (int mf = 0; mf < 2; mf++) {
#pragma unroll
            for (int r = 0; r < 4; r++) {
                int row = mf * 16 + g4 * 4 + r;
#pragma unroll
                for (int nf = 0; nf < 2; nf++) {
                    float v = mf ? (nf ? c11[r] : c10[r]) : (nf ? c01[r] : c00[r]);
                    v = silu_f(v + b2v[nf]);
                    int col = n0 + nf * 16 + l15;
                    e2u[swz128(row, col)] = f2bf(v);
                }
            }
        }
        __syncthreads();

        // ---- edge LayerNorm (fp32) + agg atomic scatter; e -> e1s ----
#pragma unroll
        for (int i = 0; i < 8; i++) {
            int e = wave * 8 + i;
            float x0 = bf2f(e2u[swz128(e, lane)]);
            float x1 = bf2f(e2u[swz128(e, lane + 64)]);
            float s = x0 + x1, s2 = x0 * x0 + x1 * x1;
#pragma unroll
            for (int off = 32; off; off >>= 1) {
                s  += __shfl_xor(s, off);
                s2 += __shfl_xor(s2, off);
            }
            float m = s * (1.0f / 128.0f);
            float va = s2 * (1.0f / 128.0f) - m * m;
            float inv = rsqrtf(va + 1e-5f);
            float y0 = (x0 - m) * inv * egl0 + ebl0;
            float y1 = (x1 - m) * inv * egl1 + ebl1;
            e1u[swz128(e, lane)]      = f2bf(y0);
            e1u[swz128(e, lane + 64)] = f2bf(y1);
            size_t rb = (size_t)rids[e] * 128;
            atomicAdd(&agg[rb + lane], y0);
            atomicAdd(&agg[rb + lane + 64], y1);
        }
        __syncthreads();

        // ---- GEMM3: p = silu(e @ cw1 + cb1) * cw2 ; scale = row-sum p ----
        f32x4 d00 = {0,0,0,0}, d01 = {0,0,0,0}, d10 = {0,0,0,0}, d11 = {0,0,0,0};
        {
            const bf16x8* A = (const bf16x8*)e1s;
#pragma unroll
            for (int kc = 0; kc < 4; kc++) {
                int ch = kc * 4 + g4;
                bf16x8 f0 = A[l15 * 16 + (ch ^ sw)];
                bf16x8 f1 = A[(l15 + 16) * 16 + (ch ^ sw)];
                d00 = __builtin_amdgcn_mfma_f32_16x16x32_bf16(f0, B3[0][kc], d00, 0, 0, 0);
                d01 = __builtin_amdgcn_mfma_f32_16x16x32_bf16(f0, B3[1][kc], d01, 0, 0, 0);
                d10 = __builtin_amdgcn_mfma_f32_16x16x32_bf16(f1, B3[0][kc], d10, 0, 0, 0);
                d11 = __builtin_amdgcn_mfma_f32_16x16x32_bf16(f1, B3[1][kc], d11, 0, 0, 0);
            }
        }
        {
            float prow[2][4];
#pragma unroll
            for (int mf = 0; mf < 2; mf++)
#pragma unroll
                for (int r = 0; r < 4; r++) prow[mf][r] = 0.0f;
#pragma unroll
            for (int mf = 0; mf < 2; mf++)
#pragma unroll
                for (int r = 0; r < 4; r++)
#pragma unroll
                    for (int nf = 0; nf < 2; nf++) {
                        float v = mf ? (nf ? d11[r] : d10[r]) : (nf ? d01[r] : d00[r]);
                        prow[mf][r] += silu_f(v + cb1v[nf]) * cw2v[nf];
                    }
#pragma unroll
            for (int mf = 0; mf < 2; mf++)
#pragma unroll
                for (int r = 0; r < 4; r++) {
                    float v = prow[mf][r];
                    v += __shfl_xor(v, 1); v += __shfl_xor(v, 2);
                    v += __shfl_xor(v, 4); v += __shfl_xor(v, 8);
                    if (l15 == 0) atomicAdd(&scalef[mf * 16 + g4 * 4 + r], v);
                }
        }
        __syncthreads();

        // ---- scatter trans + cnt ----
        if (t < 96) {
            int e = t / 3, j = t - (t / 3) * 3;
            atomicAdd(&svec[rids[e] * 3 + j], cdS[e][j] * scalef[e]);
        } else if (t < 128) {
            int e = t - 96;
            atomicAdd(&cnt[rids[e]], 1.0f);
        }
    }
}

// ---------------- Kernel 3: MFMA node kernel + coord_out -----------------
__global__ __launch_bounds__(256, 2) void node_kernel(
    const float* __restrict__ h, const unsigned short* __restrict__ hnb,
    const float* __restrict__ aggp, const float* __restrict__ coord,
    const float* __restrict__ nb1, const float* __restrict__ nb2,
    const unsigned short* __restrict__ nw1T,
    const unsigned short* __restrict__ nw2T,
    const float* __restrict__ svec, const float* __restrict__ cnt,
    float* __restrict__ hout, float* __restrict__ cout) {
    __shared__ uint4 a1s[32 * 32];   // [32 nodes][256 k] bf16, swizzled
    __shared__ uint4 nbs[32 * 16];   // hidden [32][128] bf16

    const int t    = threadIdx.x;
    const int lane = t & 63;
    const int wave = t >> 6;
    const int l15  = lane & 15;
    const int g4   = lane >> 4;
    const int n0   = wave * 32;
    const int sw   = l15 & 7;

    bf16x8 B1[2][8], B2[2][4];
    float nb1v[2], nb2v[2];
#pragma unroll
    for (int nf = 0; nf < 2; nf++) {
        int wr = n0 + nf * 16 + l15;
        const unsigned short* p1 = nw1T + wr * 256 + g4 * 8;
#pragma unroll
        for (int kc = 0; kc < 8; kc++) B1[nf][kc] = *(const bf16x8*)(p1 + kc * 32);
        const unsigned short* p2 = nw2T + wr * 128 + g4 * 8;
#pragma unroll
        for (int kc = 0; kc < 4; kc++) B2[nf][kc] = *(const bf16x8*)(p2 + kc * 32);
        nb1v[nf] = nb1[wr]; nb2v[nf] = nb2[wr];
    }
    unsigned short* nbu = (unsigned short*)nbs;

    const int NT = (NN + 31) / 32;
    for (int tile = blockIdx.x; tile < NT; tile += gridDim.x) {
        const int n0t = tile * 32;
        int nn = NN - n0t; if (nn > 32) nn = 32;

        // coord_out (independent of LDS state)
        if (t < 96) {
            int i = t / 3, j = t - (t / 3) * 3;
            int node = n0t + i;
            if (i < nn) {
                float c = fmaxf(cnt[node], 1.0f);
                cout[node * 3 + j] = coord[node * 3 + j] + svec[node * 3 + j] / c;
            }
        }
        __syncthreads();
        // stage A = [hn (bf16) | agg (fp32->bf16)]
#pragma unroll
        for (int ii = 0; ii < 4; ii++) {
            int idx = t + ii * 256;
            int rr = idx >> 5, c = idx & 31;
            int node = n0t + ((rr < nn) ? rr : 0);
            uint4 d;
            if (c < 16) {
                d = *(const uint4*)(hnb + (size_t)node * 128 + c * 8);
            } else {
                const float* ap = aggp + (size_t)node * 128 + (c - 16) * 8;
                float4 f0 = *(const float4*)ap;
                float4 f1 = *(const float4*)(ap + 4);
                d.x = f2bf(f0.x) | ((unsigned)f2bf(f0.y) << 16);
                d.y = f2bf(f0.z) | ((unsigned)f2bf(f0.w) << 16);
                d.z = f2bf(f1.x) | ((unsigned)f2bf(f1.y) << 16);
                d.w = f2bf(f1.z) | ((unsigned)f2bf(f1.w) << 16);
            }
            a1s[rr * 32 + (c ^ (rr & 7))] = d;
        }
        __syncthreads();

        f32x4 a00 = {0,0,0,0}, a01 = {0,0,0,0}, a10 = {0,0,0,0}, a11 = {0,0,0,0};
        {
            const bf16x8* A = (const bf16x8*)a1s;
#pragma unroll
            for (int kc = 0; kc < 8; kc++) {
                int ch = kc * 4 + g4;
                bf16x8 f0 = A[l15 * 32 + (ch ^ sw)];
                bf16x8 f1 = A[(l15 + 16) * 32 + (ch ^ sw)];
                a00 = __builtin_amdgcn_mfma_f32_16x16x32_bf16(f0, B1[0][kc], a00, 0, 0, 0);
                a01 = __builtin_amdgcn_mfma_f32_16x16x32_bf16(f0, B1[1][kc], a01, 0, 0, 0);
                a10 = __builtin_amdgcn_mfma_f32_16x16x32_bf16(f1, B1[0][kc], a10, 0, 0, 0);
                a11 = __builtin_amdgcn_mfma_f32_16x16x32_bf16(f1, B1[1][kc], a11, 0, 0, 0);
            }
        }
#pragma unroll
        for (int mf = 0; mf < 2; mf++) {
#pragma unroll
            for (int r = 0; r < 4; r++) {
                int row = mf * 16 + g4 * 4 + r;
#pragma unroll
                for (int nf = 0; nf < 2; nf++) {
                    float v = mf ? (nf ? a11[r] : a10[r]) : (nf ? a01[r] : a00[r]);
                    v = silu_f(v + nb1v[nf]);
                    int col = n0 + nf * 16 + l15;
                    nbu[swz128(row, col)] = f2bf(v);
                }
            }
        }
        __syncthreads();

        f32x4 c00 = {0,0,0,0}, c01 = {0,0,0,0}, c10 = {0,0,0,0}, c11 = {0,0,0,0};
        {
            const bf16x8* A = (const bf16x8*)nbs;
#pragma unroll
            for (int kc = 0; kc < 4; kc++) {
                int ch = kc * 4 + g4;
                bf16x8 f0 = A[l15 * 16 + (ch ^ sw)];
                bf16x8 f1 = A[(l15 + 16) * 16 + (ch ^ sw)];
                c00 = __builtin_amdgcn_mfma_f32_16x16x32_bf16(f0, B2[0][kc], c00, 0, 0, 0);
                c01 = __builtin_amdgcn_mfma_f32_16x16x32_bf16(f0, B2[1][kc], c01, 0, 0, 0);
                c10 = __builtin_amdgcn_mfma_f32_16x16x32_bf16(f1, B2[0][kc], c10, 0, 0, 0);
                c11 = __builtin_amdgcn_mfma_f32_16x16x32_bf16(f1, B2[1][kc], c11, 0, 0, 0);
            }
        }
#pragma unroll
        for (int mf = 0; mf < 2; mf++) {
#pragma unroll
            for (int r = 0; r < 4; r++) {
                int row = mf * 16 + g4 * 4 + r;
                if (row < nn) {
                    int node = n0t + row;
#pragma unroll
                    for (int nf = 0; nf < 2; nf++) {
                        float v = mf ? (nf ? c11[r] : c10[r]) : (nf ? c01[r] : c00[r]);
                        int col = n0 + nf * 16 + l15;
                        hout[(size_t)node * 128 + col] =
                            v + nb2v[nf] + h[(size_t)node * 128 + col];
                    }
                }
            }
        }
    }
}

extern "C" void kernel_launch(void* const* d_in, const int* in_sizes, int n_in,
                              void* d_out, int out_size, void* d_ws, size_t ws_size,
                              hipStream_t stream) {
    const float* h     = (const float*)d_in[0];
    const int*   eidx  = (const int*)d_in[1];
    const float* coord = (const float*)d_in[2];
    const float* nlg   = (const float*)d_in[3];
    const float* nlb   = (const float*)d_in[4];
    const float* elg   = (const float*)d_in[5];
    const float* elb   = (const float*)d_in[6];
    const float* ew1   = (const float*)d_in[7];
    const float* eb1   = (const float*)d_in[8];
    const float* ew2   = (const float*)d_in[9];
    const float* eb2   = (const float*)d_in[10];
    const float* nw1   = (const float*)d_in[11];
    const float* nb1   = (const float*)d_in[12];
    const float* nw2   = (const float*)d_in[13];
    const float* nb2   = (const float*)d_in[14];
    const float* cw1   = (const float*)d_in[15];
    const float* cb1   = (const float*)d_in[16];
    const float* cw2   = (const float*)d_in[17];

    float* hout = (float*)d_out;
    float* cout = (float*)d_out + (size_t)NN * 128;

    // ws layout (bytes, 16B-aligned):
    char* ws = (char*)d_ws;
    unsigned short* hnb  = (unsigned short*)(ws);                 // 12,800,000 B
    float*          agg  = (float*)(ws + 12800000);               // 25,600,000 B
    float*          svec = (float*)(ws + 38400000);               //    600,000 B
    float*          cnt  = (float*)(ws + 39000000);               //    200,000 B
    unsigned short* w1T  = (unsigned short*)(ws + 39200000);      //     65,536 B
    unsigned short* w2T  = (unsigned short*)(ws + 39265536);      //     32,768 B
    unsigned short* cw1T = (unsigned short*)(ws + 39298304);      //     32,768 B
    unsigned short* nw1T = (unsigned short*)(ws + 39331072);      //     65,536 B
    unsigned short* nw2T = (unsigned short*)(ws + 39396608);      //     32,768 B

    // zero agg|svec|cnt (contiguous)
    hipMemsetAsync(agg, 0, (size_t)25600000 + 600000 + 200000, stream);

    const int* erow = eidx;
    const int* ecol = eidx + NE;

    prep_weights<<<448, 256, 0, stream>>>(ew1, ew2, cw1, nw1, nw2,
                                          w1T, w2T, cw1T, nw1T, nw2T);
    ln_nodes_kernel<<<(NN + 3) / 4, 256, 0, stream>>>(h, nlg, nlb, hnb);
    edge_kernel<<<1024, 256, 0, stream>>>(
        hnb, erow, ecol, coord, elg, elb, ew1, eb1, eb2, cb1, cw2,
        w1T, w2T, cw1T, agg, svec, cnt);
    node_kernel<<<512, 256, 0, stream>>>(
        h, hnb, agg, coord, nb1, nb2, nw1T, nw2T, svec, cnt, hout, cout);
}